// Round 3
// baseline (4048.337 us; speedup 1.0000x reference)
//
#include <hip/hip_runtime.h>
#include <math.h>

#define B_  2048
#define S_  32
#define T_  32
#define D_  128
#define H_  256
#define G3  768
#define VT_ 256
#define BOW_ 1

typedef __attribute__((ext_vector_type(8))) short short8;
typedef __attribute__((ext_vector_type(4))) float f32x4;
typedef __attribute__((ext_vector_type(4))) unsigned short us4;
typedef __attribute__((ext_vector_type(8))) unsigned short us8;
typedef unsigned short u16;

__device__ inline u16 f2bf(float x) {
  union { float f; unsigned u; } v; v.f = x;
  unsigned r = v.u + 0x7FFFu + ((v.u >> 16) & 1u);
  return (u16)(r >> 16);
}
__device__ inline float bf2f(u16 b) {
  union { unsigned u; float f; } v; v.u = ((unsigned)b) << 16; return v.f;
}
__device__ inline int swz(int r) { return ((r ^ (r >> 3)) & 7) << 3; }
__device__ inline float sigm(float x) { return 1.f / (1.f + expf(-x)); }

// ---------------- weight transpose + split:  W[R][C] -> W^T planes [C][R] ----
struct TMat { const float* src; u16* dhi; u16* dlo; int R; int C; int tile0; };
struct TPack { TMat m[10]; };

__global__ __launch_bounds__(256)
void wsplit_t(TPack P) {
  int bx = blockIdx.x;
  TMat M = P.m[0];
  #pragma unroll
  for (int i = 1; i < 10; i++) if (bx >= P.m[i].tile0) M = P.m[i];
  int ti = bx - M.tile0;
  int tilesR = M.R >> 6;
  int rt = ti % tilesR, ct = ti / tilesR;
  int r0 = rt * 64, c0 = ct * 64;
  __shared__ float ts[64][65];
  int tid = threadIdx.x;
  int cx = tid & 63, ry = tid >> 6;
  #pragma unroll
  for (int i = 0; i < 16; i++) {
    int r = ry * 16 + i;
    ts[r][cx] = M.src[(size_t)(r0 + r) * M.C + c0 + cx];
  }
  __syncthreads();
  int rx = tid & 63, cy = tid >> 6;
  #pragma unroll
  for (int i = 0; i < 16; i++) {
    int cc = cy * 16 + i;
    float v = ts[rx][cc];
    u16 hi = f2bf(v);
    size_t o = (size_t)(c0 + cc) * M.R + r0 + rx;
    M.dhi[o] = hi;
    M.dlo[o] = f2bf(v - bf2f(hi));
  }
}

// ---------------- embedding split (no transpose) ----------------
__global__ __launch_bounds__(256)
void esplit(const float* a, const float* b, u16* ah, u16* al, u16* bh, u16* bl, int n) {
  int i = blockIdx.x * 256 + threadIdx.x;
  if (i >= 2 * n) return;
  const float* s = (i < n) ? a : b;
  u16* dh = (i < n) ? ah : bh;
  u16* dl = (i < n) ? al : bl;
  int j = (i < n) ? i : i - n;
  float v = s[j];
  u16 hi = f2bf(v);
  dh[j] = hi; dl[j] = f2bf(v - bf2f(hi));
}

// ---------------- generic plane-GEMM (2 legs) ----------------
struct PLeg {
  const u16* Ahi; const u16* Alo; const float* Af32; int lda;
  const u16* Bthi; const u16* Btlo; int ldb;
  const float* bias; void* C; int ldc; int cmode;   // 0=f32, 1=bf16
  int M, N, K;
};

__global__ __launch_bounds__(256)
void gemm_pl(PLeg l0, PLeg l1) {
  PLeg L = blockIdx.z ? l1 : l0;
  int n0 = blockIdx.x * 128; if (n0 >= L.N) return;
  int m0 = blockIdx.y * 128; if (m0 >= L.M) return;
  __shared__ u16 As[128 * 64];
  __shared__ u16 Bs[128 * 64];
  int tid = threadIdx.x;
  int lane = tid & 63, wv = tid >> 6;
  int wr = (wv >> 1) * 64, wc = (wv & 1) * 64;
  int fr = lane & 15, fk = (lane >> 4) * 8;
  f32x4 acc[4][4];
  #pragma unroll
  for (int m = 0; m < 4; m++)
    #pragma unroll
    for (int n = 0; n < 4; n++) acc[m][n] = (f32x4){0.f, 0.f, 0.f, 0.f};

  int s_row = tid >> 1, s_part = tid & 1;

  for (int k0 = 0; k0 < L.K; k0 += 32) {
    if (k0) __syncthreads();
    int swA = swz(s_row);
    if (L.Af32) {
      const float* src = L.Af32 + (size_t)(m0 + s_row) * L.lda + k0 + s_part * 16;
      #pragma unroll
      for (int q = 0; q < 4; q++) {
        f32x4 v = *(const f32x4*)(src + q * 4);
        us4 hv, lv;
        #pragma unroll
        for (int j = 0; j < 4; j++) {
          u16 h = f2bf(v[j]); hv[j] = h; lv[j] = f2bf(v[j] - bf2f(h));
        }
        *(us4*)&As[(s_row * 64 + s_part * 16 + q * 4) ^ swA]      = hv;
        *(us4*)&As[(s_row * 64 + 32 + s_part * 16 + q * 4) ^ swA] = lv;
      }
    } else {
      const u16* src = (s_part ? L.Alo : L.Ahi) + (size_t)(m0 + s_row) * L.lda + k0;
      #pragma unroll
      for (int q = 0; q < 4; q++)
        *(us8*)&As[(s_row * 64 + s_part * 32 + q * 8) ^ swA] = *(const us8*)(src + q * 8);
    }
    {
      const u16* src = (s_part ? L.Btlo : L.Bthi) + (size_t)(n0 + s_row) * L.ldb + k0;
      #pragma unroll
      for (int q = 0; q < 4; q++)
        *(us8*)&Bs[(s_row * 64 + s_part * 32 + q * 8) ^ swA] = *(const us8*)(src + q * 8);
    }
    __syncthreads();
    short8 bhi[4], blo[4];
    #pragma unroll
    for (int n = 0; n < 4; n++) {
      int c = wc + n * 16 + fr; int sw = swz(c);
      bhi[n] = *(const short8*)&Bs[(c * 64 + fk) ^ sw];
      blo[n] = *(const short8*)&Bs[(c * 64 + 32 + fk) ^ sw];
    }
    #pragma unroll
    for (int m = 0; m < 4; m++) {
      int r = wr + m * 16 + fr; int sw = swz(r);
      short8 ahi = *(const short8*)&As[(r * 64 + fk) ^ sw];
      short8 alo = *(const short8*)&As[(r * 64 + 32 + fk) ^ sw];
      #pragma unroll
      for (int n = 0; n < 4; n++) {
        acc[m][n] = __builtin_amdgcn_mfma_f32_16x16x32_bf16(ahi, bhi[n], acc[m][n], 0, 0, 0);
        acc[m][n] = __builtin_amdgcn_mfma_f32_16x16x32_bf16(ahi, blo[n], acc[m][n], 0, 0, 0);
        acc[m][n] = __builtin_amdgcn_mfma_f32_16x16x32_bf16(alo, bhi[n], acc[m][n], 0, 0, 0);
      }
    }
  }
  int rbase = (lane >> 4) * 4;
  #pragma unroll
  for (int m = 0; m < 4; m++)
    #pragma unroll
    for (int rr = 0; rr < 4; rr++) {
      int row = m0 + wr + m * 16 + rbase + rr;
      #pragma unroll
      for (int n = 0; n < 4; n++) {
        int col = n0 + wc + n * 16 + fr;
        float v = acc[m][n][rr];
        if (L.bias) v += L.bias[col];
        if (L.cmode == 0) ((float*)L.C)[(size_t)row * L.ldc + col] = v;
        else              ((u16*)L.C)[(size_t)row * L.ldc + col] = f2bf(v);
      }
    }
}

// ---------------- fused GRU step: strip-GEMM + gate epilogue ----------------
struct Seg {
  const u16* Ahi; const u16* Alo; int lda;
  const u16* Bthi; const u16* Btlo; int ldb;
  int K; int gmode;   // 0 none, 1 enc-fwd, 2 enc-bwd, 3 dec-emb
};
struct StepDesc {
  Seg seg[3]; int nseg;
  const float* b0; const float* b1;
  const float* hold; float* hnew;
  u16* hh; u16* hl;
  float* ssf; int ssmode;          // 0 none, 1 first(store), 2 last(add)
  u16* ss0h; u16* ss0l; int writeSS0;
  const int* ids; int sidx;
};

__global__ __launch_bounds__(256)
void gru_step(StepDesc d0, StepDesc d1) {
  StepDesc D = blockIdx.z ? d1 : d0;
  int j0 = blockIdx.x * 64;
  int m0 = blockIdx.y * 64;
  __shared__ u16 As[64 * 64];
  __shared__ u16 Bs[3 * 64 * 64];
  int tid = threadIdx.x;
  int lane = tid & 63, wv = tid >> 6;
  int wr = (wv >> 1) * 32, wc = (wv & 1) * 32;
  int fr = lane & 15, fk = (lane >> 4) * 8;
  // acc strips: 0=z(sum), 1=r(sum), 2=hc, 3=xc
  f32x4 acc[4][2][2];
  #pragma unroll
  for (int a = 0; a < 4; a++)
    #pragma unroll
    for (int m = 0; m < 2; m++)
      #pragma unroll
      for (int n = 0; n < 2; n++) acc[a][m][n] = (f32x4){0.f, 0.f, 0.f, 0.f};

  int a_row = tid >> 2, a_part = (tid >> 1) & 1, a_half = tid & 1;

  #pragma unroll
  for (int sg = 0; sg < 3; sg++) {
    if (sg < D.nseg) {
      Seg S = D.seg[sg];
      int grow = m0 + a_row;
      int arow;
      if (S.gmode == 0)      arow = grow;
      else if (S.gmode == 1) arow = D.ids[grow * S_ + D.sidx];
      else if (S.gmode == 2) arow = D.ids[grow * S_ + (S_ - 1 - D.sidx)];
      else                   arow = (D.sidx == 0) ? BOW_ : D.ids[grow * T_ + D.sidx - 1];
      const u16* Ap = a_part ? S.Alo : S.Ahi;
      for (int k0 = 0; k0 < S.K; k0 += 32) {
        if (!(sg == 0 && k0 == 0)) __syncthreads();
        {
          int sw = swz(a_row);
          const u16* src = Ap + (size_t)arow * S.lda + k0 + a_half * 16;
          int bse = a_row * 64 + a_part * 32 + a_half * 16;
          *(us8*)&As[(bse + 0) ^ sw] = *(const us8*)(src);
          *(us8*)&As[(bse + 8) ^ sw] = *(const us8*)(src + 8);
        }
        #pragma unroll
        for (int st = 0; st < 3; st++) {
          int n768 = st * H_ + j0 + a_row;
          const u16* srcB = (a_part ? S.Btlo : S.Bthi) + (size_t)n768 * S.ldb + k0 + a_half * 16;
          int sw = swz(a_row);
          int bse = a_row * 64 + a_part * 32 + a_half * 16;
          *(us8*)&Bs[st * 4096 + ((bse + 0) ^ sw)] = *(const us8*)(srcB);
          *(us8*)&Bs[st * 4096 + ((bse + 8) ^ sw)] = *(const us8*)(srcB + 8);
        }
        __syncthreads();
        short8 ah[2], al[2];
        #pragma unroll
        for (int m = 0; m < 2; m++) {
          int r = wr + m * 16 + fr; int sw = swz(r);
          ah[m] = *(const short8*)&As[(r * 64 + fk) ^ sw];
          al[m] = *(const short8*)&As[(r * 64 + 32 + fk) ^ sw];
        }
        #pragma unroll
        for (int st = 0; st < 3; st++) {
          int ai = (st < 2) ? st : (sg == 0 ? 2 : 3);
          #pragma unroll
          for (int n = 0; n < 2; n++) {
            int c = wc + n * 16 + fr; int sw = swz(c);
            short8 bh = *(const short8*)&Bs[st * 4096 + ((c * 64 + fk) ^ sw)];
            short8 bl = *(const short8*)&Bs[st * 4096 + ((c * 64 + 32 + fk) ^ sw)];
            #pragma unroll
            for (int m = 0; m < 2; m++) {
              acc[ai][m][n] = __builtin_amdgcn_mfma_f32_16x16x32_bf16(ah[m], bh, acc[ai][m][n], 0, 0, 0);
              acc[ai][m][n] = __builtin_amdgcn_mfma_f32_16x16x32_bf16(ah[m], bl, acc[ai][m][n], 0, 0, 0);
              acc[ai][m][n] = __builtin_amdgcn_mfma_f32_16x16x32_bf16(al[m], bh, acc[ai][m][n], 0, 0, 0);
            }
          }
        }
      }
    }
  }

  // gate epilogue
  int rbase = (lane >> 4) * 4;
  #pragma unroll
  for (int m = 0; m < 2; m++)
    #pragma unroll
    for (int rr = 0; rr < 4; rr++) {
      int b = m0 + wr + m * 16 + rbase + rr;
      #pragma unroll
      for (int n = 0; n < 2; n++) {
        int j = j0 + wc + n * 16 + fr;
        float az  = acc[0][m][n][rr];
        float ar  = acc[1][m][n][rr];
        float ahc = acc[2][m][n][rr];
        float axc = acc[3][m][n][rr];
        float z = sigm(az + D.b0[j] + D.b1[j]);
        float r = sigm(ar + D.b0[H_ + j] + D.b1[H_ + j]);
        float c = tanhf(axc + D.b0[2 * H_ + j] + r * (ahc + D.b1[2 * H_ + j]));
        size_t o = (size_t)b * H_ + j;
        float hn = z * D.hold[o] + (1.f - z) * c;
        D.hnew[o] = hn;
        u16 hi = f2bf(hn);
        D.hh[o] = hi; D.hl[o] = f2bf(hn - bf2f(hi));
        if (D.ssmode == 1) {
          D.ssf[o] = hn;
        } else if (D.ssmode == 2) {
          float v = D.ssf[o] + hn;
          D.ssf[o] = v;
          if (D.writeSS0) {
            u16 vh = f2bf(v);
            D.ss0h[o] = vh; D.ss0l[o] = f2bf(v - bf2f(vh));
          }
        }
      }
    }
}

// ---------------- attention ----------------
__global__ __launch_bounds__(256)
void attend_k(const u16* __restrict__ projbf, const float* __restrict__ ss,
              const float* __restrict__ p, const float* __restrict__ att_v,
              u16* __restrict__ ctxh, u16* __restrict__ ctxl) {
  int b = blockIdx.x;
  int tid = threadIdx.x;
  int lane = tid & 63;
  int wv = tid >> 6;
  __shared__ float e_s[S_];
  __shared__ float w_s[S_];
  float pq[4], vq[4];
  #pragma unroll
  for (int q = 0; q < 4; q++) {
    pq[q] = p[(size_t)b * H_ + q * 64 + lane];
    vq[q] = att_v[q * 64 + lane];
  }
  #pragma unroll
  for (int i = 0; i < 8; i++) {
    int s = wv * 8 + i;
    const u16* pr = projbf + ((size_t)s * B_ + b) * H_;
    float part = 0.f;
    #pragma unroll
    for (int q = 0; q < 4; q++)
      part += tanhf(bf2f(pr[q * 64 + lane]) + pq[q]) * vq[q];
    #pragma unroll
    for (int off = 32; off; off >>= 1)
      part += __shfl_xor(part, off);
    if (lane == 0) e_s[s] = part;
  }
  __syncthreads();
  float m = -1e30f;
  #pragma unroll
  for (int s = 0; s < S_; s++) m = fmaxf(m, e_s[s]);
  float den = 0.f;
  #pragma unroll
  for (int s = 0; s < S_; s++) den += expf(e_s[s] - m);
  if (tid < S_) w_s[tid] = expf(e_s[tid] - m) / den;
  __syncthreads();
  float acc = 0.f;
  #pragma unroll
  for (int s = 0; s < S_; s++)
    acc = fmaf(w_s[s], ss[((size_t)s * B_ + b) * H_ + tid], acc);
  u16 hi = f2bf(acc);
  size_t o = (size_t)b * H_ + tid;
  ctxh[o] = hi; ctxl[o] = f2bf(acc - bf2f(hi));
}

// ---------------- host ----------------
extern "C" void kernel_launch(void* const* d_in, const int* in_sizes, int n_in,
                              void* d_out, int out_size, void* d_ws, size_t ws_size,
                              hipStream_t stream) {
  const float* src_emb   = (const float*)d_in[0];
  const float* tgt_emb   = (const float*)d_in[1];
  const float* enc_f_W   = (const float*)d_in[2];
  const float* enc_f_U   = (const float*)d_in[3];
  const float* enc_f_b   = (const float*)d_in[4];
  const float* enc_b_W   = (const float*)d_in[5];
  const float* enc_b_U   = (const float*)d_in[6];
  const float* enc_b_b   = (const float*)d_in[7];
  const float* dec_W     = (const float*)d_in[8];
  const float* dec_U     = (const float*)d_in[9];
  const float* dec_b     = (const float*)d_in[10];
  const float* out_W     = (const float*)d_in[11];
  const float* out_b     = (const float*)d_in[12];
  const float* att_src_W = (const float*)d_in[13];
  const float* att_src_b = (const float*)d_in[14];
  const float* att_st_W  = (const float*)d_in[15];
  const float* att_st_b  = (const float*)d_in[16];
  const float* att_v     = (const float*)d_in[17];
  const int* source_ids  = (const int*)d_in[19];
  const int* target_ids  = (const int*)d_in[20];
  float* out = (float*)d_out;

  char* base = (char*)d_ws;
  size_t off = 0;
  auto allocB = [&](size_t bytes) { void* p = base + off; off = (off + bytes + 255) & ~255UL; return p; };
  const size_t BH = (size_t)B_ * H_;

  float* ss    = (float*)allocB((size_t)S_ * BH * 4);
  u16*  projbf = (u16*) allocB((size_t)S_ * BH * 2);
  float* pbuf  = (float*)allocB(BH * 4);
  u16* ctxh = (u16*)allocB(BH * 2);
  u16* ctxl = (u16*)allocB(BH * 2);
  u16* ss0h = (u16*)allocB(BH * 2);
  u16* ss0l = (u16*)allocB(BH * 2);
  float* hEncF[2][2]; u16* hEncH[2][2]; u16* hEncL[2][2];
  for (int d = 0; d < 2; d++)
    for (int p = 0; p < 2; p++) {
      hEncF[d][p] = (float*)allocB(BH * 4);
      hEncH[d][p] = (u16*)allocB(BH * 2);
      hEncL[d][p] = (u16*)allocB(BH * 2);
    }
  float* hDecF[2]; u16* hDecH[2]; u16* hDecL[2];
  for (int p = 0; p < 2; p++) {
    hDecF[p] = (float*)allocB(BH * 4);
    hDecH[p] = (u16*)allocB(BH * 2);
    hDecL[p] = (u16*)allocB(BH * 2);
  }
  auto planes2 = [&](size_t n, u16*& h, u16*& l) { h = (u16*)allocB(n * 2); l = (u16*)allocB(n * 2); };
  u16 *UtFh,*UtFl,*UtBh,*UtBl,*WtFh,*WtFl,*WtBh,*WtBl;
  u16 *dUth,*dUtl,*dWcth,*dWctl,*dWxth,*dWxtl;
  u16 *oWth,*oWtl,*aStth,*aSttl,*aSrth,*aSrtl;
  u16 *sEh,*sEl,*tEh,*tEl;
  planes2((size_t)G3*H_, UtFh, UtFl);   planes2((size_t)G3*H_, UtBh, UtBl);
  planes2((size_t)G3*D_, WtFh, WtFl);   planes2((size_t)G3*D_, WtBh, WtBl);
  planes2((size_t)G3*H_, dUth, dUtl);   planes2((size_t)G3*H_, dWcth, dWctl);
  planes2((size_t)G3*D_, dWxth, dWxtl);
  planes2((size_t)H_*VT_, oWth, oWtl);
  planes2((size_t)H_*H_, aStth, aSttl); planes2((size_t)H_*H_, aSrth, aSrtl);
  planes2((size_t)VT_*D_, sEh, sEl);    planes2((size_t)VT_*D_, tEh, tEl);

  // ---- weight transpose+split (1 launch, 312 tiles) ----
  TPack P;
  P.m[0] = { enc_f_U,            UtFh, UtFl, 256, 768, 0   };
  P.m[1] = { enc_b_U,            UtBh, UtBl, 256, 768, 48  };
  P.m[2] = { dec_U,              dUth, dUtl, 256, 768, 96  };
  P.m[3] = { dec_W + 128 * G3,   dWcth, dWctl, 256, 768, 144 };
  P.m[4] = { enc_f_W,            WtFh, WtFl, 128, 768, 192 };
  P.m[5] = { enc_b_W,            WtBh, WtBl, 128, 768, 216 };
  P.m[6] = { dec_W,              dWxth, dWxtl, 128, 768, 240 };
  P.m[7] = { out_W,              oWth, oWtl, 256, 256, 264 };
  P.m[8] = { att_st_W,           aStth, aSttl, 256, 256, 280 };
  P.m[9] = { att_src_W,          aSrth, aSrtl, 256, 256, 296 };
  wsplit_t<<<312, 256, 0, stream>>>(P);
  esplit<<<(2 * VT_ * D_ + 255) / 256, 256, 0, stream>>>(src_emb, tgt_emb, sEh, sEl, tEh, tEl, VT_ * D_);

  // ---- init h (parity 0) ----
  for (int d = 0; d < 2; d++) {
    hipMemsetAsync(hEncF[d][0], 0, BH * 4, stream);
    hipMemsetAsync(hEncH[d][0], 0, BH * 2, stream);
    hipMemsetAsync(hEncL[d][0], 0, BH * 2, stream);
  }

  // ---- encoder ----
  for (int s = 0; s < S_; s++) {
    int p = s & 1;
    StepDesc dd[2];
    for (int d = 0; d < 2; d++) {
      StepDesc& D = dd[d];
      D.seg[0] = { hEncH[d][p], hEncL[d][p], H_, d ? UtBh : UtFh, d ? UtBl : UtFl, H_, H_, 0 };
      D.seg[1] = { sEh, sEl, D_, d ? WtBh : WtFh, d ? WtBl : WtFl, D_, D_, d ? 2 : 1 };
      D.seg[2] = D.seg[1];
      D.nseg = 2;
      D.b0 = d ? enc_b_b : enc_f_b;
      D.b1 = (d ? enc_b_b : enc_f_b) + G3;
      D.hold = hEncF[d][p]; D.hnew = hEncF[d][p ^ 1];
      D.hh = hEncH[d][p ^ 1]; D.hl = hEncL[d][p ^ 1];
      int pos = d ? (S_ - 1 - s) : s;
      D.ssf = ss + (size_t)pos * BH;
      D.ssmode = (s < S_ / 2) ? 1 : 2;
      D.ss0h = ss0h; D.ss0l = ss0l;
      D.writeSS0 = (d == 1 && s == S_ - 1) ? 1 : 0;
      D.ids = source_ids; D.sidx = s;
    }
    gru_step<<<dim3(4, 32, 2), 256, 0, stream>>>(dd[0], dd[1]);
  }

  // ---- proj (bf16) + p0 ----
  {
    PLeg proj = { nullptr, nullptr, ss, H_, aSrth, aSrtl, H_, att_src_b,
                  projbf, H_, 1, S_ * B_, H_, H_ };
    PLeg p0   = { nullptr, nullptr, ss, H_, aStth, aSttl, H_, att_st_b,
                  pbuf, H_, 0, B_, H_, H_ };
    gemm_pl<<<dim3(2, 512, 2), 256, 0, stream>>>(proj, p0);
  }
  attend_k<<<B_, 256, 0, stream>>>(projbf, ss, pbuf, att_v, ctxh, ctxl);

  // ---- decoder ----
  for (int t = 0; t < T_; t++) {
    int p = t & 1;
    StepDesc D;
    D.seg[0] = { t ? hDecH[p] : ss0h, t ? hDecL[p] : ss0l, H_, dUth, dUtl, H_, H_, 0 };
    D.seg[1] = { ctxh, ctxl, H_, dWcth, dWctl, H_, H_, 0 };
    D.seg[2] = { tEh, tEl, D_, dWxth, dWxtl, D_, D_, 3 };
    D.nseg = 3;
    D.b0 = dec_b; D.b1 = dec_b + G3;
    D.hold = t ? hDecF[p] : ss;
    D.hnew = hDecF[p ^ 1];
    D.hh = hDecH[p ^ 1]; D.hl = hDecL[p ^ 1];
    D.ssf = nullptr; D.ssmode = 0;
    D.ss0h = nullptr; D.ss0l = nullptr; D.writeSS0 = 0;
    D.ids = target_ids; D.sidx = t;
    gru_step<<<dim3(4, 32, 1), 256, 0, stream>>>(D, D);

    PLeg LO = { hDecH[p ^ 1], hDecL[p ^ 1], nullptr, H_, oWth, oWtl, H_, out_b,
                out + (size_t)t * VT_, T_ * VT_, 0, B_, VT_, H_ };
    PLeg LP = { hDecH[p ^ 1], hDecL[p ^ 1], nullptr, H_, aStth, aSttl, H_, att_st_b,
                pbuf, H_, 0, B_, H_, H_ };
    gemm_pl<<<dim3(2, 16, 2), 256, 0, stream>>>(LO, LP);

    if (t < T_ - 1)
      attend_k<<<B_, 256, 0, stream>>>(projbf, ss, pbuf, att_v, ctxh, ctxl);
  }
}

// Round 4
// 3648.425 us; speedup vs baseline: 1.1096x; 1.1096x over previous
//
#include <hip/hip_runtime.h>
#include <math.h>

#define B_  2048
#define S_  32
#define T_  32
#define D_  128
#define H_  256
#define G3  768
#define VT_ 256
#define BOW_ 1

typedef __attribute__((ext_vector_type(8))) short short8;
typedef __attribute__((ext_vector_type(4))) float f32x4;
typedef __attribute__((ext_vector_type(8))) unsigned short us8;
typedef unsigned short u16;

__device__ inline u16 f2bf(float x) {
  union { float f; unsigned u; } v; v.f = x;
  unsigned r = v.u + 0x7FFFu + ((v.u >> 16) & 1u);
  return (u16)(r >> 16);
}
__device__ inline float bf2f(u16 b) {
  union { unsigned u; float f; } v; v.u = ((unsigned)b) << 16; return v.f;
}
__device__ inline int swz(int r) { return ((r ^ (r >> 3)) & 7) << 3; }
__device__ inline float sigm(float x) { return 1.f / (1.f + expf(-x)); }

// ---------------- weight transpose + split ----------------
struct TMat { const float* src; u16* dhi; u16* dlo; int R; int C; int tile0; };
struct TPack { TMat m[10]; };

__global__ __launch_bounds__(256)
void wsplit_t(TPack P) {
  int bx = blockIdx.x;
  TMat M = P.m[0];
  #pragma unroll
  for (int i = 1; i < 10; i++) if (bx >= P.m[i].tile0) M = P.m[i];
  int ti = bx - M.tile0;
  int tilesR = M.R >> 6;
  int rt = ti % tilesR, ct = ti / tilesR;
  int r0 = rt * 64, c0 = ct * 64;
  __shared__ float ts[64][65];
  int tid = threadIdx.x;
  int cx = tid & 63, ry = tid >> 6;
  #pragma unroll
  for (int i = 0; i < 16; i++) {
    int r = ry * 16 + i;
    ts[r][cx] = M.src[(size_t)(r0 + r) * M.C + c0 + cx];
  }
  __syncthreads();
  int rx = tid & 63, cy = tid >> 6;
  #pragma unroll
  for (int i = 0; i < 16; i++) {
    int cc = cy * 16 + i;
    float v = ts[rx][cc];
    u16 hi = f2bf(v);
    size_t o = (size_t)(c0 + cc) * M.R + r0 + rx;
    M.dhi[o] = hi;
    M.dlo[o] = f2bf(v - bf2f(hi));
  }
}

__global__ __launch_bounds__(256)
void esplit(const float* a, const float* b, u16* ah, u16* al, u16* bh, u16* bl, int n) {
  int i = blockIdx.x * 256 + threadIdx.x;
  if (i >= 2 * n) return;
  const float* s = (i < n) ? a : b;
  u16* dh = (i < n) ? ah : bh;
  u16* dl = (i < n) ? al : bl;
  int j = (i < n) ? i : i - n;
  float v = s[j];
  u16 hi = f2bf(v);
  dh[j] = hi; dl[j] = f2bf(v - bf2f(hi));
}

// ---------------- plane GEMM (proj/p0/LP/LO) ----------------
struct PLeg {
  const u16* Ahi; const u16* Alo; int lda;
  const u16* Bthi; const u16* Btlo; int ldb;
  const float* bias; void* C; int ldc; int cmode;  // 0=f32, 1=bf16, 2=logits-layout
  int M, N, K;
};

__global__ __launch_bounds__(256)
void gemm_pl(PLeg l0, PLeg l1) {
  PLeg L = blockIdx.z ? l1 : l0;
  int n0 = blockIdx.x * 128; if (n0 >= L.N) return;
  int m0 = blockIdx.y * 128; if (m0 >= L.M) return;
  __shared__ u16 As[128 * 64];
  __shared__ u16 Bs[128 * 64];
  int tid = threadIdx.x;
  int lane = tid & 63, wv = tid >> 6;
  int wr = (wv >> 1) * 64, wc = (wv & 1) * 64;
  int fr = lane & 15, fk = (lane >> 4) * 8;
  f32x4 acc[4][4];
  #pragma unroll
  for (int m = 0; m < 4; m++)
    #pragma unroll
    for (int n = 0; n < 4; n++) acc[m][n] = (f32x4){0.f, 0.f, 0.f, 0.f};

  int s_row = tid >> 1, s_part = tid & 1;

  for (int k0 = 0; k0 < L.K; k0 += 32) {
    if (k0) __syncthreads();
    int swA = swz(s_row);
    {
      const u16* src = (s_part ? L.Alo : L.Ahi) + (size_t)(m0 + s_row) * L.lda + k0;
      #pragma unroll
      for (int q = 0; q < 4; q++)
        *(us8*)&As[(s_row * 64 + s_part * 32 + q * 8) ^ swA] = *(const us8*)(src + q * 8);
    }
    {
      const u16* src = (s_part ? L.Btlo : L.Bthi) + (size_t)(n0 + s_row) * L.ldb + k0;
      #pragma unroll
      for (int q = 0; q < 4; q++)
        *(us8*)&Bs[(s_row * 64 + s_part * 32 + q * 8) ^ swA] = *(const us8*)(src + q * 8);
    }
    __syncthreads();
    short8 bhi[4], blo[4];
    #pragma unroll
    for (int n = 0; n < 4; n++) {
      int c = wc + n * 16 + fr; int sw = swz(c);
      bhi[n] = *(const short8*)&Bs[(c * 64 + fk) ^ sw];
      blo[n] = *(const short8*)&Bs[(c * 64 + 32 + fk) ^ sw];
    }
    #pragma unroll
    for (int m = 0; m < 4; m++) {
      int r = wr + m * 16 + fr; int sw = swz(r);
      short8 ahi = *(const short8*)&As[(r * 64 + fk) ^ sw];
      short8 alo = *(const short8*)&As[(r * 64 + 32 + fk) ^ sw];
      #pragma unroll
      for (int n = 0; n < 4; n++) {
        acc[m][n] = __builtin_amdgcn_mfma_f32_16x16x32_bf16(ahi, bhi[n], acc[m][n], 0, 0, 0);
        acc[m][n] = __builtin_amdgcn_mfma_f32_16x16x32_bf16(ahi, blo[n], acc[m][n], 0, 0, 0);
        acc[m][n] = __builtin_amdgcn_mfma_f32_16x16x32_bf16(alo, bhi[n], acc[m][n], 0, 0, 0);
      }
    }
  }
  int rbase = (lane >> 4) * 4;
  #pragma unroll
  for (int m = 0; m < 4; m++)
    #pragma unroll
    for (int rr = 0; rr < 4; rr++) {
      int row = m0 + wr + m * 16 + rbase + rr;
      #pragma unroll
      for (int n = 0; n < 4; n++) {
        int col = n0 + wc + n * 16 + fr;
        float v = acc[m][n][rr];
        if (L.bias) v += L.bias[col];
        if (L.cmode == 0)      ((float*)L.C)[(size_t)row * L.ldc + col] = v;
        else if (L.cmode == 1) ((u16*)L.C)[(size_t)row * L.ldc + col] = f2bf(v);
        else {
          size_t o = (((size_t)(row & (B_ - 1))) * T_ + (row >> 11)) * VT_ + col;
          ((float*)L.C)[o] = v;
        }
      }
    }
}

// ---------------- fused GRU step (barrier-free K loop) ----------------
struct GruDesc {
  const u16 *a0H, *a0L;       // h planes (lda 256)
  const u16 *a1H, *a1L;       // enc: emb (lda 128) | dec: ctx (lda 256)
  const u16 *a2H, *a2L;       // dec: emb (lda 128)
  const u16 *b0H, *b0L;       // U^T planes (ldb 256)
  const u16 *b1H, *b1L;       // enc: W^T (ldb 128) | dec: Wc^T (ldb 256)
  const u16 *b2H, *b2L;       // dec: Wx^T (ldb 128)
  const float *bias0, *bias1;
  const float *hold;          // f32 hold (null -> use holdH/L planes)
  const u16 *holdH, *holdL;
  float *hnew;
  u16 *hh, *hl;
  u16 *ssH, *ssL;             // enc: pre-sliced to pos
  const int *ids;
  int ssmode;                 // 0 none, 1 store, 2 finalize(add)
  int sidx, rev;
};

template<int MODE>   // 0 = encoder (K=256+128), 1 = decoder (K=256+256+128)
__global__ __launch_bounds__(256)
void gru_step(GruDesc d0, GruDesc d1) {
  GruDesc D = blockIdx.z ? d1 : d0;
  constexpr int KT  = MODE ? 640 : 384;
  constexpr int KT8 = KT / 8;
  __shared__ u16 As[2 * 32 * KT];

  int j0 = blockIdx.x * 64;
  int m0 = blockIdx.y * 32;
  int tid = threadIdx.x;
  int lane = tid & 63, wv = tid >> 6;
  int fr = lane & 15, kq = lane >> 4;
  int jn = j0 + wv * 16 + fr;

  // ---- stage A panel (32 rows x KT, hi+lo) ----
  constexpr int SLOTS = 2 * 32 * KT8;
  constexpr int PER_T = SLOTS / 256;
  #pragma unroll
  for (int i = 0; i < PER_T; i++) {
    int s = tid + i * 256;
    int p = s / (32 * KT8);
    int rem = s - p * (32 * KT8);
    int row = rem / KT8;
    int kb = rem - row * KT8;
    int k = kb * 8;
    const u16* src;
    if (MODE == 0) {
      if (k < 256) src = (p ? D.a0L : D.a0H) + (size_t)(m0 + row) * 256 + k;
      else {
        int ar = D.ids[(m0 + row) * S_ + (D.rev ? (S_ - 1 - D.sidx) : D.sidx)];
        src = (p ? D.a1L : D.a1H) + (size_t)ar * 128 + (k - 256);
      }
    } else {
      if (k < 256)      src = (p ? D.a0L : D.a0H) + (size_t)(m0 + row) * 256 + k;
      else if (k < 512) src = (p ? D.a1L : D.a1H) + (size_t)(m0 + row) * 256 + (k - 256);
      else {
        int ar = (D.sidx == 0) ? BOW_ : D.ids[(m0 + row) * T_ + D.sidx - 1];
        src = (p ? D.a2L : D.a2H) + (size_t)ar * 128 + (k - 512);
      }
    }
    *(us8*)&As[(s ^ (row & 7)) * 8] = *(const us8*)src;
  }
  __syncthreads();

  // acc: 0=z 1=r 2=hc 3=xc
  f32x4 acc[4][2];
  #pragma unroll
  for (int a = 0; a < 4; a++)
    #pragma unroll
    for (int m = 0; m < 2; m++) acc[a][m] = (f32x4){0.f, 0.f, 0.f, 0.f};

  int arow_slot[2];
  #pragma unroll
  for (int m = 0; m < 2; m++) arow_slot[m] = (m * 16 + fr) * KT8 + kq;

  auto kstep = [&](int k0, int bk, const u16* bHp, const u16* bLp, int ldb, int ai2) {
    short8 ah[2], al[2];
    #pragma unroll
    for (int m = 0; m < 2; m++) {
      int sl = (arow_slot[m] + (k0 >> 3)) ^ (fr & 7);
      ah[m] = *(const short8*)&As[sl * 8];
      sl = (arow_slot[m] + 32 * KT8 + (k0 >> 3)) ^ (fr & 7);
      al[m] = *(const short8*)&As[sl * 8];
    }
    #pragma unroll
    for (int st = 0; st < 3; st++) {
      size_t ro = (size_t)(st * 256 + jn) * ldb + bk + kq * 8;
      short8 bh = *(const short8*)(bHp + ro);
      short8 bl = *(const short8*)(bLp + ro);
      int ai = (st < 2) ? st : ai2;
      #pragma unroll
      for (int m = 0; m < 2; m++) {
        acc[ai][m] = __builtin_amdgcn_mfma_f32_16x16x32_bf16(ah[m], bh, acc[ai][m], 0, 0, 0);
        acc[ai][m] = __builtin_amdgcn_mfma_f32_16x16x32_bf16(ah[m], bl, acc[ai][m], 0, 0, 0);
        acc[ai][m] = __builtin_amdgcn_mfma_f32_16x16x32_bf16(al[m], bh, acc[ai][m], 0, 0, 0);
      }
    }
  };

  #pragma unroll
  for (int k0 = 0; k0 < 256; k0 += 32) kstep(k0, k0, D.b0H, D.b0L, 256, 2);
  if (MODE == 0) {
    #pragma unroll
    for (int k0 = 256; k0 < 384; k0 += 32) kstep(k0, k0 - 256, D.b1H, D.b1L, 128, 3);
  } else {
    #pragma unroll
    for (int k0 = 256; k0 < 512; k0 += 32) kstep(k0, k0 - 256, D.b1H, D.b1L, 256, 3);
    #pragma unroll
    for (int k0 = 512; k0 < 640; k0 += 32) kstep(k0, k0 - 512, D.b2H, D.b2L, 128, 3);
  }

  // ---- gate epilogue ----
  int rbase = kq * 4;
  int j = jn;
  float bz = D.bias0[j] + D.bias1[j];
  float br = D.bias0[H_ + j] + D.bias1[H_ + j];
  float bxc = D.bias0[2 * H_ + j];
  float bhc = D.bias1[2 * H_ + j];
  #pragma unroll
  for (int m = 0; m < 2; m++)
    #pragma unroll
    for (int rr = 0; rr < 4; rr++) {
      int b = m0 + m * 16 + rbase + rr;
      size_t o = (size_t)b * H_ + j;
      float z = sigm(acc[0][m][rr] + bz);
      float r = sigm(acc[1][m][rr] + br);
      float c = tanhf(acc[3][m][rr] + bxc + r * (acc[2][m][rr] + bhc));
      float hprev = D.hold ? D.hold[o] : (bf2f(D.holdH[o]) + bf2f(D.holdL[o]));
      float hn = z * hprev + (1.f - z) * c;
      D.hnew[o] = hn;
      u16 hi = f2bf(hn);
      D.hh[o] = hi; D.hl[o] = f2bf(hn - bf2f(hi));
      if (MODE == 0) {
        if (D.ssmode == 1) {
          u16 vh = f2bf(hn);
          D.ssH[o] = vh; D.ssL[o] = f2bf(hn - bf2f(vh));
        } else if (D.ssmode == 2) {
          float v = bf2f(D.ssH[o]) + bf2f(D.ssL[o]) + hn;
          u16 vh = f2bf(v);
          D.ssH[o] = vh; D.ssL[o] = f2bf(v - bf2f(vh));
        }
      }
    }
}

// ---------------- attention ----------------
__global__ __launch_bounds__(256)
void attend_k(const u16* __restrict__ projbf, const u16* __restrict__ ssH,
              const float* __restrict__ p, const float* __restrict__ att_v,
              u16* __restrict__ ctxh, u16* __restrict__ ctxl) {
  int b = blockIdx.x;
  int tid = threadIdx.x;
  int lane = tid & 63;
  int wv = tid >> 6;
  __shared__ float e_s[S_];
  __shared__ float w_s[S_];
  float pq[4], vq[4];
  #pragma unroll
  for (int q = 0; q < 4; q++) {
    pq[q] = p[(size_t)b * H_ + q * 64 + lane];
    vq[q] = att_v[q * 64 + lane];
  }
  #pragma unroll
  for (int i = 0; i < 8; i++) {
    int s = wv * 8 + i;
    const u16* pr = projbf + ((size_t)s * B_ + b) * H_;
    float part = 0.f;
    #pragma unroll
    for (int q = 0; q < 4; q++)
      part += tanhf(bf2f(pr[q * 64 + lane]) + pq[q]) * vq[q];
    #pragma unroll
    for (int off = 32; off; off >>= 1)
      part += __shfl_xor(part, off);
    if (lane == 0) e_s[s] = part;
  }
  __syncthreads();
  float m = -1e30f;
  #pragma unroll
  for (int s = 0; s < S_; s++) m = fmaxf(m, e_s[s]);
  float den = 0.f;
  #pragma unroll
  for (int s = 0; s < S_; s++) den += expf(e_s[s] - m);
  if (tid < S_) w_s[tid] = expf(e_s[tid] - m) / den;
  __syncthreads();
  float acc = 0.f;
  #pragma unroll
  for (int s = 0; s < S_; s++)
    acc = fmaf(w_s[s], bf2f(ssH[((size_t)s * B_ + b) * H_ + tid]), acc);
  u16 hi = f2bf(acc);
  size_t o = (size_t)b * H_ + tid;
  ctxh[o] = hi; ctxl[o] = f2bf(acc - bf2f(hi));
}

// ---------------- host ----------------
extern "C" void kernel_launch(void* const* d_in, const int* in_sizes, int n_in,
                              void* d_out, int out_size, void* d_ws, size_t ws_size,
                              hipStream_t stream) {
  const float* src_emb   = (const float*)d_in[0];
  const float* tgt_emb   = (const float*)d_in[1];
  const float* enc_f_W   = (const float*)d_in[2];
  const float* enc_f_U   = (const float*)d_in[3];
  const float* enc_f_b   = (const float*)d_in[4];
  const float* enc_b_W   = (const float*)d_in[5];
  const float* enc_b_U   = (const float*)d_in[6];
  const float* enc_b_b   = (const float*)d_in[7];
  const float* dec_W     = (const float*)d_in[8];
  const float* dec_U     = (const float*)d_in[9];
  const float* dec_b     = (const float*)d_in[10];
  const float* out_W     = (const float*)d_in[11];
  const float* out_b     = (const float*)d_in[12];
  const float* att_src_W = (const float*)d_in[13];
  const float* att_src_b = (const float*)d_in[14];
  const float* att_st_W  = (const float*)d_in[15];
  const float* att_st_b  = (const float*)d_in[16];
  const float* att_v     = (const float*)d_in[17];
  const int* source_ids  = (const int*)d_in[19];
  const int* target_ids  = (const int*)d_in[20];
  float* out = (float*)d_out;

  char* base = (char*)d_ws;
  size_t off = 0;
  auto allocB = [&](size_t bytes) { void* p = base + off; off = (off + bytes + 255) & ~255UL; return p; };
  const size_t BH = (size_t)B_ * H_;

  u16* ssH    = (u16*)allocB((size_t)S_ * BH * 2);
  u16* ssL    = (u16*)allocB((size_t)S_ * BH * 2);
  u16* projbf = (u16*)allocB((size_t)S_ * BH * 2);
  float* pbuf = (float*)allocB(BH * 4);
  u16* ctxh = (u16*)allocB(BH * 2);
  u16* ctxl = (u16*)allocB(BH * 2);

  float* encF0 = (float*)allocB(2 * BH * 4);   // parity 0, dirs contiguous
  u16*  encPl0 = (u16*)allocB(4 * BH * 2);     // d0H d0L d1H d1L
  float* encF1 = (float*)allocB(2 * BH * 4);
  u16*  encPl1 = (u16*)allocB(4 * BH * 2);
  float* encF[2][2]  = { { encF0, encF0 + BH }, { encF1, encF1 + BH } };   // [parity][dir]
  u16*  encH[2][2]   = { { encPl0, encPl0 + 2 * BH }, { encPl1, encPl1 + 2 * BH } };
  u16*  encL[2][2]   = { { encPl0 + BH, encPl0 + 3 * BH }, { encPl1 + BH, encPl1 + 3 * BH } };

  float* hDecF[2] = { (float*)allocB(BH * 4), (float*)allocB(BH * 4) };
  u16* hAllH = (u16*)allocB((size_t)T_ * BH * 2);
  u16* hAllL = (u16*)allocB((size_t)T_ * BH * 2);

  auto planes2 = [&](size_t n, u16*& h, u16*& l) { h = (u16*)allocB(n * 2); l = (u16*)allocB(n * 2); };
  u16 *UtFh,*UtFl,*UtBh,*UtBl,*WtFh,*WtFl,*WtBh,*WtBl;
  u16 *dUth,*dUtl,*dWcth,*dWctl,*dWxth,*dWxtl;
  u16 *oWth,*oWtl,*aStth,*aSttl,*aSrth,*aSrtl;
  u16 *sEh,*sEl,*tEh,*tEl;
  planes2((size_t)G3*H_, UtFh, UtFl);   planes2((size_t)G3*H_, UtBh, UtBl);
  planes2((size_t)G3*D_, WtFh, WtFl);   planes2((size_t)G3*D_, WtBh, WtBl);
  planes2((size_t)G3*H_, dUth, dUtl);   planes2((size_t)G3*H_, dWcth, dWctl);
  planes2((size_t)G3*D_, dWxth, dWxtl);
  planes2((size_t)H_*VT_, oWth, oWtl);
  planes2((size_t)H_*H_, aStth, aSttl); planes2((size_t)H_*H_, aSrth, aSrtl);
  planes2((size_t)VT_*D_, sEh, sEl);    planes2((size_t)VT_*D_, tEh, tEl);

  TPack P;
  P.m[0] = { enc_f_U,          UtFh, UtFl, 256, 768, 0   };
  P.m[1] = { enc_b_U,          UtBh, UtBl, 256, 768, 48  };
  P.m[2] = { dec_U,            dUth, dUtl, 256, 768, 96  };
  P.m[3] = { dec_W + 128 * G3, dWcth, dWctl, 256, 768, 144 };
  P.m[4] = { enc_f_W,          WtFh, WtFl, 128, 768, 192 };
  P.m[5] = { enc_b_W,          WtBh, WtBl, 128, 768, 216 };
  P.m[6] = { dec_W,            dWxth, dWxtl, 128, 768, 240 };
  P.m[7] = { out_W,            oWth, oWtl, 256, 256, 264 };
  P.m[8] = { att_st_W,         aStth, aSttl, 256, 256, 280 };
  P.m[9] = { att_src_W,        aSrth, aSrtl, 256, 256, 296 };
  wsplit_t<<<312, 256, 0, stream>>>(P);
  esplit<<<(2 * VT_ * D_ + 255) / 256, 256, 0, stream>>>(src_emb, tgt_emb, sEh, sEl, tEh, tEl, VT_ * D_);

  hipMemsetAsync(encF0, 0, 2 * BH * 4, stream);
  hipMemsetAsync(encPl0, 0, 4 * BH * 2, stream);

  // ---- encoder ----
  for (int s = 0; s < S_; s++) {
    int p = s & 1;
    GruDesc dd[2];
    for (int d = 0; d < 2; d++) {
      GruDesc& D = dd[d];
      D.a0H = encH[p][d]; D.a0L = encL[p][d];
      D.a1H = sEh; D.a1L = sEl;
      D.a2H = nullptr; D.a2L = nullptr;
      D.b0H = d ? UtBh : UtFh; D.b0L = d ? UtBl : UtFl;
      D.b1H = d ? WtBh : WtFh; D.b1L = d ? WtBl : WtFl;
      D.b2H = nullptr; D.b2L = nullptr;
      D.bias0 = d ? enc_b_b : enc_f_b;
      D.bias1 = (d ? enc_b_b : enc_f_b) + G3;
      D.hold = encF[p][d]; D.holdH = nullptr; D.holdL = nullptr;
      D.hnew = encF[p ^ 1][d];
      D.hh = encH[p ^ 1][d]; D.hl = encL[p ^ 1][d];
      int pos = d ? (S_ - 1 - s) : s;
      D.ssH = ssH + (size_t)pos * BH; D.ssL = ssL + (size_t)pos * BH;
      D.ids = source_ids;
      D.ssmode = (s < S_ / 2) ? 1 : 2;
      D.sidx = s; D.rev = d;
    }
    gru_step<0><<<dim3(4, 64, 2), 256, 0, stream>>>(dd[0], dd[1]);
  }

  // ---- proj (bf16) + p0 ----
  {
    PLeg proj = { ssH, ssL, H_, aSrth, aSrtl, H_, att_src_b, projbf, H_, 1, S_ * B_, H_, H_ };
    PLeg p0   = { ssH, ssL, H_, aStth, aSttl, H_, att_st_b,  pbuf,   H_, 0, B_,      H_, H_ };
    gemm_pl<<<dim3(2, 512, 2), 256, 0, stream>>>(proj, p0);
  }
  attend_k<<<B_, 256, 0, stream>>>(projbf, ssH, pbuf, att_v, ctxh, ctxl);

  // ---- decoder ----
  for (int t = 0; t < T_; t++) {
    int p = t & 1;
    GruDesc D = {};
    D.a0H = t ? hAllH + (size_t)(t - 1) * BH : ssH;
    D.a0L = t ? hAllL + (size_t)(t - 1) * BH : ssL;
    D.a1H = ctxh; D.a1L = ctxl;
    D.a2H = tEh;  D.a2L = tEl;
    D.b0H = dUth;  D.b0L = dUtl;
    D.b1H = dWcth; D.b1L = dWctl;
    D.b2H = dWxth; D.b2L = dWxtl;
    D.bias0 = dec_b; D.bias1 = dec_b + G3;
    if (t == 0) { D.hold = nullptr; D.holdH = ssH; D.holdL = ssL; }
    else        { D.hold = hDecF[p]; D.holdH = nullptr; D.holdL = nullptr; }
    D.hnew = hDecF[p ^ 1];
    D.hh = hAllH + (size_t)t * BH; D.hl = hAllL + (size_t)t * BH;
    D.ssH = nullptr; D.ssL = nullptr;
    D.ids = target_ids;
    D.ssmode = 0; D.sidx = t; D.rev = 0;
    gru_step<1><<<dim3(4, 64, 1), 256, 0, stream>>>(D, D);

    if (t < T_ - 1) {
      PLeg LP = { hAllH + (size_t)t * BH, hAllL + (size_t)t * BH, H_,
                  aStth, aSttl, H_, att_st_b, pbuf, H_, 0, B_, H_, H_ };
      gemm_pl<<<dim3(2, 16, 1), 256, 0, stream>>>(LP, LP);
      attend_k<<<B_, 256, 0, stream>>>(projbf, ssH, pbuf, att_v, ctxh, ctxl);
    }
  }

  // ---- batched logits ----
  {
    PLeg LO = { hAllH, hAllL, H_, oWth, oWtl, H_, out_b, out, 0, 2, T_ * B_, VT_, H_ };
    gemm_pl<<<dim3(2, 512, 1), 256, 0, stream>>>(LO, LO);
  }
}